// Round 12
// baseline (252.267 us; speedup 1.0000x reference)
//
#include <hip/hip_runtime.h>
#include <stdint.h>

// ---------------- types & helpers ----------------
typedef __attribute__((ext_vector_type(8))) short     s16x8;
typedef __attribute__((ext_vector_type(8))) __bf16    bf16v8;
typedef __attribute__((ext_vector_type(4))) float     f32x4;
typedef __attribute__((ext_vector_type(4))) unsigned short u16x4;
typedef __attribute__((ext_vector_type(2))) unsigned int  u32x2;

__device__ __forceinline__ unsigned short f2bf(float f) {
  unsigned int u = __builtin_bit_cast(unsigned int, f);
  unsigned int r = u + 0x7FFFu + ((u >> 16) & 1u);
  return (unsigned short)(r >> 16);
}
__device__ __forceinline__ float bf2f(unsigned short h) {
  return __builtin_bit_cast(float, (unsigned int)h << 16);
}
__device__ __forceinline__ unsigned int cvtpk(float lo, float hi) {
  unsigned int r;
  asm("v_cvt_pk_bf16_f32 %0, %1, %2" : "=v"(r) : "v"(lo), "v"(hi));
  return r;
}
__device__ __forceinline__ f32x4 mfma16(s16x8 a, s16x8 b, f32x4 c) {
  return __builtin_amdgcn_mfma_f32_16x16x32_bf16(
      __builtin_bit_cast(bf16v8, a), __builtin_bit_cast(bf16v8, b), c, 0, 0, 0);
}
__device__ __forceinline__ void gload16(const void* g, void* l) {
  __builtin_amdgcn_global_load_lds(
      (const __attribute__((address_space(1))) unsigned int*)(uintptr_t)g,
      (__attribute__((address_space(3))) unsigned int*)(uintptr_t)l, 16, 0, 0);
}

#define HH 12
#define NSEQ 2048
#define DD 64
// Q scale: (1/8) * log2(e)  -> P = exp2(score) directly
#define QSCALE 0.1803368801111137f

// ---------------- fused prep: x->bf16 | qkv_w^T | o_w^T (hi only) ----------
__global__ void k_prep(const float* __restrict__ x, unsigned short* __restrict__ xhi,
                       const float* __restrict__ wq, unsigned short* __restrict__ wqh,
                       const float* __restrict__ wo, unsigned short* __restrict__ woh) {
  const int b = blockIdx.x;
  if (b < 6144) {                       // x -> bf16, vectorized x4
    int i = b * 256 + threadIdx.x;
    f32x4 v = ((const f32x4*)x)[i];
    u16x4 h;
#pragma unroll
    for (int j = 0; j < 4; ++j) h[j] = f2bf(v[j]);
    *(u16x4*)&xhi[i * 4] = h;
  } else if (b < 6144 + 6912) {         // qkv_w [768][2304] -> [2304][768]
    int i = (b - 6144) * 256 + threadIdx.x;
    if (i < 2304 * 768) {
      int n = i / 768, k = i - n * 768;
      wqh[i] = f2bf(wq[(size_t)k * 2304 + n]);
    }
  } else {                              // o_w [768][768] -> transposed
    int i = (b - 13056) * 256 + threadIdx.x;
    int n = i / 768, k = i - n * 768;
    woh[i] = f2bf(wo[(size_t)k * 768 + n]);
  }
}

// ---------------- GEMM (m97 structure): C[M,N] = A[M,K] * Bt[N,K]^T ----------------
// mode 0: outF[m*Nn+n] = acc + bias[n]      (fp32, coalesced)
// mode 1: QK scatter: gn<768 -> Q(*QSCALE), else K  (bf16, 32B segments)
// mode 2: V^T: row gm = h*64+d, col gn = b*2048+nn -> Vt coalesced; bias[gm]
__global__ __launch_bounds__(256) void k_gemm(
    const unsigned short* __restrict__ Ahi,
    const unsigned short* __restrict__ Bt,
    const float* __restrict__ bias, float* __restrict__ outF,
    unsigned short* __restrict__ Qb, unsigned short* __restrict__ Kb,
    unsigned short* __restrict__ Vt, int M, int Nn, int K, int mode) {
  __shared__ __align__(16) unsigned short As[128 * 32];
  __shared__ __align__(16) unsigned short Bs[128 * 32];
  const int tid = threadIdx.x;
  const int w = tid >> 6, l = tid & 63;
  const int ntn = Nn >> 7;
  const int cpx = gridDim.x >> 3;
  const int bid = (blockIdx.x & 7) * cpx + (blockIdx.x >> 3);  // T1 swizzle
  const int bm = bid / ntn, bn = bid - bm * ntn;
  const int m0 = bm << 7, n0 = bn << 7;
  const int wm = w >> 1, wn = w & 1;
  const int lr = (l >> 4) << 2, lc = l & 15, lk = (l >> 4) << 3;
  const int srow = l >> 2;
  const int scol = (l & 3) << 3;

  f32x4 acc[4][4];
#pragma unroll
  for (int i = 0; i < 4; ++i)
#pragma unroll
    for (int j = 0; j < 4; ++j) acc[i][j] = (f32x4){0.f, 0.f, 0.f, 0.f};

  unsigned short* lA = &As[w * 512 + l * 8];
  unsigned short* lB = &Bs[w * 512 + l * 8];

  const unsigned short* gA = Ahi + (size_t)(m0 + w * 16 + srow) * K + scol;
  const unsigned short* gB = Bt  + (size_t)(n0 + w * 16 + srow) * K + scol;
  for (int kb = 0; kb < K; kb += 32) {
    gload16(gA + kb, lA);
    gload16(gA + (size_t)64 * K + kb, lA + 2048);
    gload16(gB + kb, lB);
    gload16(gB + (size_t)64 * K + kb, lB + 2048);
    __syncthreads();
    s16x8 af[4], bfr[4];
#pragma unroll
    for (int am = 0; am < 4; ++am)
      af[am] = *(const s16x8*)&As[(wm * 64 + am * 16 + lc) * 32 + lk];
#pragma unroll
    for (int an = 0; an < 4; ++an)
      bfr[an] = *(const s16x8*)&Bs[(wn * 64 + an * 16 + lc) * 32 + lk];
#pragma unroll
    for (int am = 0; am < 4; ++am)
#pragma unroll
      for (int an = 0; an < 4; ++an)
        acc[am][an] = mfma16(af[am], bfr[an], acc[am][an]);
    __syncthreads();
  }

#pragma unroll
  for (int am = 0; am < 4; ++am) {
#pragma unroll
    for (int an = 0; an < 4; ++an) {
#pragma unroll
      for (int r = 0; r < 4; ++r) {
        int gm = m0 + wm * 64 + am * 16 + lr + r;
        int gn = n0 + wn * 64 + an * 16 + lc;
        if (mode == 0) {
          outF[(size_t)gm * Nn + gn] = acc[am][an][r] + bias[gn];
        } else if (mode == 1) {
          float v = acc[am][an][r] + bias[gn];
          int b = gm >> 11, nn = gm & (NSEQ - 1);
          if (gn < 768) {
            int h = gn >> 6, d = gn & 63;
            Qb[((size_t)(b * HH + h) * NSEQ + nn) * DD + d] = f2bf(v * QSCALE);
          } else {
            int h = (gn - 768) >> 6, d = gn & 63;
            Kb[((size_t)(b * HH + h) * NSEQ + nn) * DD + d] = f2bf(v);
          }
        } else {
          // V^T: gm = h*64+d (0..767), gn = b*2048+nn
          float v = acc[am][an][r] + bias[gm];
          int b = gn >> 11, nn = gn & (NSEQ - 1);
          Vt[((size_t)(b * 768 + gm)) * NSEQ + nn] = f2bf(v);
        }
      }
    }
  }
}

// ---------------- flash attention: LDS-staged K/V, fixed-max softmax --------
__global__ __launch_bounds__(256) void k_attn(
    const unsigned short* __restrict__ Qb, const unsigned short* __restrict__ Kb,
    const unsigned short* __restrict__ Vt, unsigned short* __restrict__ O) {
  __shared__ __align__(16) unsigned short Ks[64 * DD];   // [key][d]
  __shared__ __align__(16) unsigned short Vs[64 * DD];   // [d][key]
  __shared__ __align__(16) unsigned short P_lds[4][16][72];
  const int l = threadIdx.x & 63;
  const int w = threadIdx.x >> 6;
  const int qblk = 31 - (int)(blockIdx.x / 48);
  const int bh = blockIdx.x % 48;
  const int qbase = (qblk << 6) + (w << 4);
  const int lg = l >> 4;
  const int lr = lg << 2, lc = l & 15, lk = lg << 3;

  const unsigned short* Qp = Qb + (size_t)bh * NSEQ * DD;
  const unsigned short* Kp = Kb + (size_t)bh * NSEQ * DD;
  const unsigned short* Vp = Vt + (size_t)bh * DD * NSEQ;

  s16x8 aq[2];
#pragma unroll
  for (int kk = 0; kk < 2; ++kk)
    aq[kk] = *(const s16x8*)&Qp[(size_t)(qbase + lc) * DD + kk * 32 + lk];

  f32x4 acc[4];
#pragma unroll
  for (int dt = 0; dt < 4; ++dt) acc[dt] = (f32x4){0.f, 0.f, 0.f, 0.f};
  float lpart = 0.f;

  const int nkt = qblk + 1;
  for (int kt = 0; kt < nkt; ++kt) {
    const int kb0 = kt << 6;
    __syncthreads();
#pragma unroll
    for (int j2 = 0; j2 < 2; ++j2) {
      const int u = (2 * w + j2) * 64 + l;
      const int r = u >> 3;
      const int src = ((u & 7) ^ (r & 7)) << 3;
      gload16(Kp + (size_t)(kb0 + r) * DD + src, (void*)&Ks[u * 8]);
      gload16(Vp + (size_t)r * NSEQ + kb0 + src, (void*)&Vs[u * 8]);
    }
    asm volatile("s_waitcnt vmcnt(0)" ::: "memory");
    __syncthreads();
    f32x4 s[4];
#pragma unroll
    for (int nt = 0; nt < 4; ++nt) s[nt] = (f32x4){0.f, 0.f, 0.f, 0.f};
#pragma unroll
    for (int nt = 0; nt < 4; ++nt) {
#pragma unroll
      for (int kk = 0; kk < 2; ++kk) {
        s16x8 bk = *(const s16x8*)&Ks[(nt * 16 + lc) * DD +
                                      (((kk * 4 + lg) ^ (lc & 7)) << 3)];
        s[nt] = mfma16(bk, aq[kk], s[nt]);
      }
    }
    s16x8 bv[4][2];
#pragma unroll
    for (int dt = 0; dt < 4; ++dt)
#pragma unroll
      for (int ks = 0; ks < 2; ++ks)
        bv[dt][ks] = *(const s16x8*)&Vs[(dt * 16 + lc) * DD +
                                        (((ks * 4 + lg) ^ (lc & 7)) << 3)];
    if (kb0 + 63 > qbase) {
      const int qg = qbase + lc;
#pragma unroll
      for (int nt = 0; nt < 4; ++nt)
#pragma unroll
        for (int r = 0; r < 4; ++r)
          if (kb0 + nt * 16 + lr + r > qg) s[nt][r] = -1e30f;
    }
#pragma unroll
    for (int nt = 0; nt < 4; ++nt)
#pragma unroll
      for (int r = 0; r < 4; ++r) {
        float pv = exp2f(s[nt][r]);
        s[nt][r] = pv;
        lpart += pv;
      }
#pragma unroll
    for (int nt = 0; nt < 4; ++nt) {
      u32x2 pk;
      pk[0] = cvtpk(s[nt][0], s[nt][1]);
      pk[1] = cvtpk(s[nt][2], s[nt][3]);
      *(u32x2*)&P_lds[w][lc][nt * 16 + lr] = pk;
    }
    asm volatile("s_waitcnt lgkmcnt(0)" ::: "memory");
    __builtin_amdgcn_sched_barrier(0);
    s16x8 pa[2];
#pragma unroll
    for (int ks = 0; ks < 2; ++ks)
      pa[ks] = *(const s16x8*)&P_lds[w][lc][ks * 32 + lk];
#pragma unroll
    for (int dt = 0; dt < 4; ++dt)
#pragma unroll
      for (int ks = 0; ks < 2; ++ks)
        acc[dt] = mfma16(pa[ks], bv[dt][ks], acc[dt]);
  }
  float lrun = lpart;
  lrun += __shfl_xor(lrun, 16);
  lrun += __shfl_xor(lrun, 32);
  const int h = bh % HH, b = bh / HH;
  const float inv = 1.0f / lrun;
  const float i0 = __shfl(inv, lr + 0), i1 = __shfl(inv, lr + 1);
  const float i2 = __shfl(inv, lr + 2), i3 = __shfl(inv, lr + 3);
  const float ir[4] = {i0, i1, i2, i3};
#pragma unroll
  for (int r = 0; r < 4; ++r) {
#pragma unroll
    for (int dt = 0; dt < 4; ++dt)
      O[((size_t)(b * NSEQ + qbase + lr + r)) * 768 + h * 64 + dt * 16 + lc] =
          f2bf(acc[dt][r] * ir[r]);
  }
}

// ---------------- launch ----------------
extern "C" void kernel_launch(void* const* d_in, const int* in_sizes, int n_in,
                              void* d_out, int out_size, void* d_ws, size_t ws_size,
                              hipStream_t stream) {
  const float* x     = (const float*)d_in[0];
  const float* qkv_w = (const float*)d_in[2];
  const float* qkv_b = (const float*)d_in[3];
  const float* o_w   = (const float*)d_in[4];
  const float* o_b   = (const float*)d_in[5];
  float* out = (float*)d_out;

  unsigned short* Xhi = (unsigned short*)d_ws;
  unsigned short* Xlo = Xhi + 8192 * 768;          // slot kept (unused)
  unsigned short* Wqh = Xlo + 8192 * 768;
  unsigned short* Wql = Wqh + 2304 * 768;          // slot kept (unused)
  unsigned short* Woh = Wql + 2304 * 768;
  unsigned short* Wol = Woh + 768 * 768;           // slot kept (unused)
  unsigned short* Qb  = Wol + 768 * 768;
  unsigned short* Kb  = Qb + (size_t)4 * HH * NSEQ * DD;
  unsigned short* Vt  = Kb + (size_t)4 * HH * NSEQ * DD;
  unsigned short* O   = Vt + (size_t)4 * HH * NSEQ * DD;

  k_prep<<<6144 + 6912 + 2304, 256, 0, stream>>>(x, Xhi, qkv_w, Wqh, o_w, Woh);
  // QK projection: M=8192, N=1536 (Q|K), scatter epilogue
  k_gemm<<<64 * 12, 256, 0, stream>>>(Xhi, Wqh, qkv_b, nullptr,
                                      Qb, Kb, nullptr, 8192, 1536, 768, 1);
  // V^T projection: swapped operands, M=768 (h*64+d), N=8192 (tokens), coalesced
  k_gemm<<<6 * 64, 256, 0, stream>>>(Wqh + (size_t)1536 * 768, Xhi, qkv_b + 1536,
                                     nullptr, nullptr, nullptr, Vt, 768, 8192, 768, 2);
  k_attn<<<1536, 256, 0, stream>>>(Qb, Kb, Vt, O);
  // output projection
  k_gemm<<<64 * 6, 256, 0, stream>>>(O, Woh, o_b, out,
                                     nullptr, nullptr, nullptr, 8192, 768, 768, 0);
}

// Round 13
// 232.581 us; speedup vs baseline: 1.0846x; 1.0846x over previous
//
#include <hip/hip_runtime.h>
#include <stdint.h>

// ---------------- types & helpers ----------------
typedef __attribute__((ext_vector_type(8))) short     s16x8;
typedef __attribute__((ext_vector_type(8))) __bf16    bf16v8;
typedef __attribute__((ext_vector_type(4))) float     f32x4;
typedef __attribute__((ext_vector_type(4))) unsigned short u16x4;
typedef __attribute__((ext_vector_type(2))) unsigned int  u32x2;

__device__ __forceinline__ unsigned short f2bf(float f) {
  unsigned int u = __builtin_bit_cast(unsigned int, f);
  unsigned int r = u + 0x7FFFu + ((u >> 16) & 1u);
  return (unsigned short)(r >> 16);
}
__device__ __forceinline__ float bf2f(unsigned short h) {
  return __builtin_bit_cast(float, (unsigned int)h << 16);
}
__device__ __forceinline__ unsigned int cvtpk(float lo, float hi) {
  unsigned int r;
  asm("v_cvt_pk_bf16_f32 %0, %1, %2" : "=v"(r) : "v"(lo), "v"(hi));
  return r;
}
__device__ __forceinline__ f32x4 mfma16(s16x8 a, s16x8 b, f32x4 c) {
  return __builtin_amdgcn_mfma_f32_16x16x32_bf16(
      __builtin_bit_cast(bf16v8, a), __builtin_bit_cast(bf16v8, b), c, 0, 0, 0);
}
__device__ __forceinline__ void gload16(const void* g, void* l) {
  __builtin_amdgcn_global_load_lds(
      (const __attribute__((address_space(1))) unsigned int*)(uintptr_t)g,
      (__attribute__((address_space(3))) unsigned int*)(uintptr_t)l, 16, 0, 0);
}

#define HH 12
#define NSEQ 2048
#define DD 64
// Q scale: (1/8) * log2(e)  -> P = exp2(score) directly
#define QSCALE 0.1803368801111137f

// ---------------- fused prep: x->bf16 | qkv_w^T | o_w^T ----------
__global__ void k_prep(const float* __restrict__ x, unsigned short* __restrict__ xhi,
                       const float* __restrict__ wq, unsigned short* __restrict__ wqh,
                       const float* __restrict__ wo, unsigned short* __restrict__ woh) {
  const int b = blockIdx.x;
  if (b < 6144) {                       // x -> bf16, vectorized x4
    int i = b * 256 + threadIdx.x;
    f32x4 v = ((const f32x4*)x)[i];
    u16x4 h;
#pragma unroll
    for (int j = 0; j < 4; ++j) h[j] = f2bf(v[j]);
    *(u16x4*)&xhi[i * 4] = h;
  } else if (b < 6144 + 6912) {         // qkv_w [768][2304] -> [2304][768]
    int i = (b - 6144) * 256 + threadIdx.x;
    if (i < 2304 * 768) {
      int n = i / 768, k = i - n * 768;
      wqh[i] = f2bf(wq[(size_t)k * 2304 + n]);
    }
  } else {                              // o_w [768][768] -> transposed
    int i = (b - 13056) * 256 + threadIdx.x;
    int n = i / 768, k = i - n * 768;
    woh[i] = f2bf(wo[(size_t)k * 768 + n]);
  }
}

// ---------------- GEMM, 2-phase double-buffered staging (T3-minimum) -------
// C[M,N] = A[M,K] * Bt[N,K]^T
// mode 0: outF[m*Nn+n] = acc + bias[n]
// mode 1: QKV scatter: gn in [0,768)=Q(*QSCALE) [768,1536)=K [1536,2304)=V^T
__global__ __launch_bounds__(256) void k_gemm(
    const unsigned short* __restrict__ Ahi,
    const unsigned short* __restrict__ Bt,
    const float* __restrict__ bias, float* __restrict__ outF,
    unsigned short* __restrict__ Qb, unsigned short* __restrict__ Kb,
    unsigned short* __restrict__ Vt, int M, int Nn, int K, int mode) {
  __shared__ __align__(16) unsigned short As[2][128 * 32];
  __shared__ __align__(16) unsigned short Bs[2][128 * 32];
  const int tid = threadIdx.x;
  const int w = tid >> 6, l = tid & 63;
  const int ntn = Nn >> 7;
  const int cpx = gridDim.x >> 3;
  const int bid = (blockIdx.x & 7) * cpx + (blockIdx.x >> 3);  // T1 swizzle
  const int bm = bid / ntn, bn = bid - bm * ntn;
  const int m0 = bm << 7, n0 = bn << 7;
  const int wm = w >> 1, wn = w & 1;
  const int lr = (l >> 4) << 2, lc = l & 15, lk = (l >> 4) << 3;
  const int srow = l >> 2;
  const int scol = (l & 3) << 3;

  f32x4 acc[4][4];
#pragma unroll
  for (int i = 0; i < 4; ++i)
#pragma unroll
    for (int j = 0; j < 4; ++j) acc[i][j] = (f32x4){0.f, 0.f, 0.f, 0.f};

  const int so = w * 512 + l * 8;       // per-thread staging offset (elements)
  const unsigned short* gA = Ahi + (size_t)(m0 + w * 16 + srow) * K + scol;
  const unsigned short* gB = Bt  + (size_t)(n0 + w * 16 + srow) * K + scol;

  // prologue: stage tile 0 into buffer 0
  gload16(gA, &As[0][so]);
  gload16(gA + (size_t)64 * K, &As[0][so + 2048]);
  gload16(gB, &Bs[0][so]);
  gload16(gB + (size_t)64 * K, &Bs[0][so + 2048]);
  asm volatile("s_waitcnt vmcnt(0)" ::: "memory");
  __syncthreads();

  const int nk = K >> 5;
  int cur = 0;
  for (int t = 0; t < nk; ++t) {
    // issue next tile's staging BEFORE computing current (latency hides)
    if (t + 1 < nk) {
      const int kb = (t + 1) << 5;
      gload16(gA + kb, &As[cur ^ 1][so]);
      gload16(gA + (size_t)64 * K + kb, &As[cur ^ 1][so + 2048]);
      gload16(gB + kb, &Bs[cur ^ 1][so]);
      gload16(gB + (size_t)64 * K + kb, &Bs[cur ^ 1][so + 2048]);
    }
    s16x8 af[4], bfr[4];
#pragma unroll
    for (int am = 0; am < 4; ++am)
      af[am] = *(const s16x8*)&As[cur][(wm * 64 + am * 16 + lc) * 32 + lk];
#pragma unroll
    for (int an = 0; an < 4; ++an)
      bfr[an] = *(const s16x8*)&Bs[cur][(wn * 64 + an * 16 + lc) * 32 + lk];
#pragma unroll
    for (int am = 0; am < 4; ++am)
#pragma unroll
      for (int an = 0; an < 4; ++an)
        acc[am][an] = mfma16(af[am], bfr[an], acc[am][an]);
    if (t + 1 < nk) {
      asm volatile("s_waitcnt vmcnt(0)" ::: "memory");
      __syncthreads();
      cur ^= 1;
    }
  }

#pragma unroll
  for (int am = 0; am < 4; ++am) {
#pragma unroll
    for (int an = 0; an < 4; ++an) {
#pragma unroll
      for (int r = 0; r < 4; ++r) {
        int gm = m0 + wm * 64 + am * 16 + lr + r;
        int gn = n0 + wn * 64 + an * 16 + lc;
        if (mode == 0) {
          outF[(size_t)gm * Nn + gn] = acc[am][an][r] + bias[gn];
        } else {
          float v = acc[am][an][r] + bias[gn];
          int t2 = gn / 768;
          int rem = gn - t2 * 768;
          int h = rem >> 6, d = rem & 63;
          int b = gm >> 11, nn = gm & (NSEQ - 1);
          if (t2 == 0)
            Qb[((size_t)(b * HH + h) * NSEQ + nn) * DD + d] = f2bf(v * QSCALE);
          else if (t2 == 1)
            Kb[((size_t)(b * HH + h) * NSEQ + nn) * DD + d] = f2bf(v);
          else
            Vt[((size_t)(b * HH + h) * DD + d) * NSEQ + nn] = f2bf(v);
        }
      }
    }
  }
}

// ---------------- flash attention: LDS-staged K/V, fixed-max softmax --------
__global__ __launch_bounds__(256) void k_attn(
    const unsigned short* __restrict__ Qb, const unsigned short* __restrict__ Kb,
    const unsigned short* __restrict__ Vt, unsigned short* __restrict__ O) {
  __shared__ __align__(16) unsigned short Ks[64 * DD];   // [key][d]
  __shared__ __align__(16) unsigned short Vs[64 * DD];   // [d][key]
  __shared__ __align__(16) unsigned short P_lds[4][16][72];
  const int l = threadIdx.x & 63;
  const int w = threadIdx.x >> 6;
  const int qblk = 31 - (int)(blockIdx.x / 48);
  const int bh = blockIdx.x % 48;
  const int qbase = (qblk << 6) + (w << 4);
  const int lg = l >> 4;
  const int lr = lg << 2, lc = l & 15, lk = lg << 3;

  const unsigned short* Qp = Qb + (size_t)bh * NSEQ * DD;
  const unsigned short* Kp = Kb + (size_t)bh * NSEQ * DD;
  const unsigned short* Vp = Vt + (size_t)bh * DD * NSEQ;

  s16x8 aq[2];
#pragma unroll
  for (int kk = 0; kk < 2; ++kk)
    aq[kk] = *(const s16x8*)&Qp[(size_t)(qbase + lc) * DD + kk * 32 + lk];

  f32x4 acc[4];
#pragma unroll
  for (int dt = 0; dt < 4; ++dt) acc[dt] = (f32x4){0.f, 0.f, 0.f, 0.f};
  float lpart = 0.f;

  const int nkt = qblk + 1;
  for (int kt = 0; kt < nkt; ++kt) {
    const int kb0 = kt << 6;
    __syncthreads();
#pragma unroll
    for (int j2 = 0; j2 < 2; ++j2) {
      const int u = (2 * w + j2) * 64 + l;
      const int r = u >> 3;
      const int src = ((u & 7) ^ (r & 7)) << 3;
      gload16(Kp + (size_t)(kb0 + r) * DD + src, (void*)&Ks[u * 8]);
      gload16(Vp + (size_t)r * NSEQ + kb0 + src, (void*)&Vs[u * 8]);
    }
    asm volatile("s_waitcnt vmcnt(0)" ::: "memory");
    __syncthreads();
    f32x4 s[4];
#pragma unroll
    for (int nt = 0; nt < 4; ++nt) s[nt] = (f32x4){0.f, 0.f, 0.f, 0.f};
#pragma unroll
    for (int nt = 0; nt < 4; ++nt) {
#pragma unroll
      for (int kk = 0; kk < 2; ++kk) {
        s16x8 bk = *(const s16x8*)&Ks[(nt * 16 + lc) * DD +
                                      (((kk * 4 + lg) ^ (lc & 7)) << 3)];
        s[nt] = mfma16(bk, aq[kk], s[nt]);
      }
    }
    s16x8 bv[4][2];
#pragma unroll
    for (int dt = 0; dt < 4; ++dt)
#pragma unroll
      for (int ks = 0; ks < 2; ++ks)
        bv[dt][ks] = *(const s16x8*)&Vs[(dt * 16 + lc) * DD +
                                        (((ks * 4 + lg) ^ (lc & 7)) << 3)];
    if (kb0 + 63 > qbase) {
      const int qg = qbase + lc;
#pragma unroll
      for (int nt = 0; nt < 4; ++nt)
#pragma unroll
        for (int r = 0; r < 4; ++r)
          if (kb0 + nt * 16 + lr + r > qg) s[nt][r] = -1e30f;
    }
#pragma unroll
    for (int nt = 0; nt < 4; ++nt)
#pragma unroll
      for (int r = 0; r < 4; ++r) {
        float pv = exp2f(s[nt][r]);
        s[nt][r] = pv;
        lpart += pv;
      }
#pragma unroll
    for (int nt = 0; nt < 4; ++nt) {
      u32x2 pk;
      pk[0] = cvtpk(s[nt][0], s[nt][1]);
      pk[1] = cvtpk(s[nt][2], s[nt][3]);
      *(u32x2*)&P_lds[w][lc][nt * 16 + lr] = pk;
    }
    asm volatile("s_waitcnt lgkmcnt(0)" ::: "memory");
    __builtin_amdgcn_sched_barrier(0);
    s16x8 pa[2];
#pragma unroll
    for (int ks = 0; ks < 2; ++ks)
      pa[ks] = *(const s16x8*)&P_lds[w][lc][ks * 32 + lk];
#pragma unroll
    for (int dt = 0; dt < 4; ++dt)
#pragma unroll
      for (int ks = 0; ks < 2; ++ks)
        acc[dt] = mfma16(pa[ks], bv[dt][ks], acc[dt]);
  }
  float lrun = lpart;
  lrun += __shfl_xor(lrun, 16);
  lrun += __shfl_xor(lrun, 32);
  const int h = bh % HH, b = bh / HH;
  const float inv = 1.0f / lrun;
  const float i0 = __shfl(inv, lr + 0), i1 = __shfl(inv, lr + 1);
  const float i2 = __shfl(inv, lr + 2), i3 = __shfl(inv, lr + 3);
  const float ir[4] = {i0, i1, i2, i3};
#pragma unroll
  for (int r = 0; r < 4; ++r) {
#pragma unroll
    for (int dt = 0; dt < 4; ++dt)
      O[((size_t)(b * NSEQ + qbase + lr + r)) * 768 + h * 64 + dt * 16 + lc] =
          f2bf(acc[dt][r] * ir[r]);
  }
}

// ---------------- launch ----------------
extern "C" void kernel_launch(void* const* d_in, const int* in_sizes, int n_in,
                              void* d_out, int out_size, void* d_ws, size_t ws_size,
                              hipStream_t stream) {
  const float* x     = (const float*)d_in[0];
  const float* qkv_w = (const float*)d_in[2];
  const float* qkv_b = (const float*)d_in[3];
  const float* o_w   = (const float*)d_in[4];
  const float* o_b   = (const float*)d_in[5];
  float* out = (float*)d_out;

  unsigned short* Xhi = (unsigned short*)d_ws;
  unsigned short* Xlo = Xhi + 8192 * 768;          // slot kept (unused)
  unsigned short* Wqh = Xlo + 8192 * 768;
  unsigned short* Wql = Wqh + 2304 * 768;          // slot kept (unused)
  unsigned short* Woh = Wql + 2304 * 768;
  unsigned short* Wol = Woh + 768 * 768;           // slot kept (unused)
  unsigned short* Qb  = Wol + 768 * 768;
  unsigned short* Kb  = Qb + (size_t)4 * HH * NSEQ * DD;
  unsigned short* Vt  = Kb + (size_t)4 * HH * NSEQ * DD;
  unsigned short* O   = Vt + (size_t)4 * HH * NSEQ * DD;

  k_prep<<<6144 + 6912 + 2304, 256, 0, stream>>>(x, Xhi, qkv_w, Wqh, o_w, Woh);
  // QKV projection: combined, single pass, 3-way scatter epilogue
  k_gemm<<<64 * 18, 256, 0, stream>>>(Xhi, Wqh, qkv_b, nullptr,
                                      Qb, Kb, Vt, 8192, 2304, 768, 1);
  k_attn<<<1536, 256, 0, stream>>>(Qb, Kb, Vt, O);
  // output projection
  k_gemm<<<64 * 6, 256, 0, stream>>>(O, Woh, o_b, out,
                                     nullptr, nullptr, nullptr, 8192, 768, 768, 0);
}